// Round 6
// baseline (2220.921 us; speedup 1.0000x reference)
//
#include <hip/hip_runtime.h>
#include <hip/hip_bf16.h>

#define NN 50000
#define NE 600000
#define GG 782     // ceil((NN/16)/4) gemm blocks
#define PGRID 2048 // persistent grid for work-stealing kernels

typedef __attribute__((ext_vector_type(8))) short short8;     // 8 bf16 (4 VGPRs)
typedef __attribute__((ext_vector_type(8))) _Float16 half8;   // 8 fp16
typedef __attribute__((ext_vector_type(4))) float floatx4;    // 4 f32 acc

__device__ __forceinline__ short bf16_bits(float v) {
    __hip_bfloat16 h = __float2bfloat16(v);
    return *reinterpret_cast<short*>(&h);
}

// ---------------- init: zero count/pub/ctrs + detect layout + convert weights ----------------
__global__ void k_init_cvt(const int* __restrict__ raw, int* __restrict__ count,
                           int* __restrict__ flag, int* __restrict__ pub,
                           int* __restrict__ ctrs, const float* __restrict__ wp1,
                           const float* __restrict__ w1, const float* __restrict__ w2,
                           __hip_bfloat16* __restrict__ wcatb, __hip_bfloat16* __restrict__ w1b,
                           __hip_bfloat16* __restrict__ w2b) {
    int i = blockIdx.x * blockDim.x + threadIdx.x;
    if (i < NN) count[i] = 0;
    if (i < 98) pub[i] = 0;
    if (i < 3) ctrs[i] = 0;
    if (i < 16384) {
        int r = i >> 7, c = i & 127;
        float v = (r < 64) ? wp1[r * 256 + c] : wp1[(r - 64) * 256 + 128 + c];
        wcatb[i] = __float2bfloat16(v);
    } else if (i < 32768) {
        w1b[i - 16384] = __float2bfloat16(w1[i - 16384]);
    } else if (i < 49152) {
        w2b[i - 32768] = __float2bfloat16(w2[i - 32768]);
    }
    if (blockIdx.x == 0) {
        if (threadIdx.x == 0) *flag = 0;
        __syncthreads();
        int any = 0;
        for (int j = threadIdx.x; j < 1024; j += 256) any |= raw[2 * j + 1];
        if (any) atomicOr(flag, 1);  // flag=1 -> int32 layout
    }
}

// ---------------- merged: gemm_uv (blocks < GG) + degree count (rest) ----------------
__global__ __launch_bounds__(256) void k_uv_count(
    const float* __restrict__ x, const __hip_bfloat16* __restrict__ Wb,
    const float* __restrict__ bp1, _Float16* __restrict__ uvh,
    __hip_bfloat16* __restrict__ xb, const int* __restrict__ raw,
    const int* __restrict__ flag, int* __restrict__ count) {
    if (blockIdx.x >= GG) {
        int e = (blockIdx.x - GG) * blockDim.x + threadIdx.x;
        if (e < NE) {
            int d = (*flag) ? raw[NE + e] : (int)((const long long*)raw)[NE + e];
            atomicAdd(&count[d], 1);
        }
        return;
    }
    const int lane = threadIdx.x & 63;
    const int wave = threadIdx.x >> 6;
    const int col = lane & 15;
    const int quad = lane >> 4;

    short8 bfrag[4][8];
    const short* wp = (const short*)Wb;
#pragma unroll
    for (int tt = 0; tt < 8; ++tt) {
        int row = tt * 16 + col;
#pragma unroll
        for (int kk = 0; kk < 4; ++kk)
            bfrag[kk][tt] = *(const short8*)(wp + row * 128 + kk * 32 + quad * 8);
    }
    int tile = blockIdx.x * 4 + wave;
    if (tile >= NN / 16) return;
    int base = tile * 16;

    floatx4 acc[8];
#pragma unroll
    for (int t = 0; t < 8; ++t) acc[t] = (floatx4){0.f, 0.f, 0.f, 0.f};
#pragma unroll
    for (int kk = 0; kk < 4; ++kk) {
        const float* xrow = x + (size_t)(base + col) * 128 + kk * 32 + quad * 8;
        float4 f0 = ((const float4*)xrow)[0];
        float4 f1 = ((const float4*)xrow)[1];
        short8 afrag;
        afrag[0] = bf16_bits(f0.x); afrag[1] = bf16_bits(f0.y);
        afrag[2] = bf16_bits(f0.z); afrag[3] = bf16_bits(f0.w);
        afrag[4] = bf16_bits(f1.x); afrag[5] = bf16_bits(f1.y);
        afrag[6] = bf16_bits(f1.z); afrag[7] = bf16_bits(f1.w);
        *(short8*)((short*)xb + (size_t)(base + col) * 128 + kk * 32 + quad * 8) = afrag;
#pragma unroll
        for (int tt = 0; tt < 8; ++tt)
            acc[tt] = __builtin_amdgcn_mfma_f32_16x16x32_bf16(afrag, bfrag[kk][tt], acc[tt], 0, 0, 0);
    }
#pragma unroll
    for (int tt = 0; tt < 8; ++tt) {
        int n = tt * 16 + col;
        float badd = (tt >= 4) ? bp1[n - 64] : 0.f;
#pragma unroll
        for (int r = 0; r < 4; ++r) {
            int row = base + quad * 4 + r;
            uvh[(size_t)row * 128 + n] = (_Float16)(acc[tt][r] + badd);
        }
    }
}

// ---------------- single-kernel scan (decoupled lookback) + finalize ----------------
// pub[b] = block_total + 1 (0 = not ready). 98 blocks co-resident -> spin is safe.
__global__ __launch_bounds__(512) void k_scan(const int* __restrict__ count,
                                              int* __restrict__ rowptr,
                                              int* __restrict__ cursor,
                                              int* __restrict__ pub) {
    __shared__ int s[512];
    __shared__ int pref[128];
    int tid = threadIdx.x, b = blockIdx.x;
    int i = b * 512 + tid;
    int c0 = (i < NN) ? count[i] : 0;
    s[tid] = c0;
    __syncthreads();
    for (int off = 1; off < 512; off <<= 1) {
        int t = (tid >= off) ? s[tid - off] : 0;
        __syncthreads();
        s[tid] += t;
        __syncthreads();
    }
    int incl_local = s[tid];
    if (tid == 511) atomicExch(&pub[b], s[511] + 1);  // publish block total
    // lookback: gather totals of all predecessor blocks
    if (tid < 128) pref[tid] = 0;
    if (tid < b) {
        int v;
        while ((v = atomicAdd(&pub[tid], 0)) == 0) __builtin_amdgcn_s_sleep(4);
        pref[tid] = v - 1;
    }
    __syncthreads();
    for (int off = 64; off > 0; off >>= 1) {
        if (tid < off) pref[tid] += pref[tid + off];
        __syncthreads();
    }
    int bp = pref[0];
    if (i < NN) {
        int incl = incl_local + bp;
        rowptr[i + 1] = incl;
        cursor[i] = incl - c0;
        if (i == 0) rowptr[0] = 0;
    }
}

// CSR fill from raw edges: meta[pos] = {src, junk} (policy fills .y)
__global__ void k_fill(const int* __restrict__ raw, const int* __restrict__ flag,
                       int* __restrict__ cursor, int2* __restrict__ meta) {
    int e = blockIdx.x * blockDim.x + threadIdx.x;
    if (e >= NE) return;
    int s, d;
    if (*flag) {
        s = raw[e];
        d = raw[NE + e];
    } else {
        const long long* r64 = (const long long*)raw;
        s = (int)r64[e];
        d = (int)r64[NE + e];
    }
    int pos = atomicAdd(&cursor[d], 1);
    meta[pos] = make_int2(s, 0);
}

// ---------------- policy MLP in CSR order: work-stealing waves, 16 groups x 4 lanes ----------------
__global__ __launch_bounds__(256) void k_policy_csr(
    const _Float16* __restrict__ uvh, const float* __restrict__ wp2,
    const float* __restrict__ bp2, const int* __restrict__ rowptr,
    int2* __restrict__ meta, float* __restrict__ deg, int* __restrict__ ctr) {
    const int lane = threadIdx.x & 63;
    const int g = lane >> 2, c = lane & 3;  // 16 edge-groups of 4 lanes
    float w2v[16];
    const float4* w2p = (const float4*)(wp2 + c * 16);
#pragma unroll
    for (int q = 0; q < 4; ++q) {
        float4 w = w2p[q];
        w2v[q * 4 + 0] = w.x; w2v[q * 4 + 1] = w.y;
        w2v[q * 4 + 2] = w.z; w2v[q * 4 + 3] = w.w;
    }
    const float b2 = bp2[0];
    for (;;) {
        int wid;
        if (lane == 0) wid = atomicAdd(ctr, 1);
        wid = __shfl(wid, 0, 64);
        if (wid >= NN) break;
        // v'[dst] (b1 folded): lane c holds features [c*16, c*16+16)
        half8 vh0 = *(const half8*)(uvh + (size_t)wid * 128 + 64 + c * 16);
        half8 vh1 = *(const half8*)(uvh + (size_t)wid * 128 + 64 + c * 16 + 8);
        float vv[16];
#pragma unroll
        for (int j = 0; j < 8; ++j) { vv[j] = (float)vh0[j]; vv[8 + j] = (float)vh1[j]; }
        int beg = rowptr[wid], end = rowptr[wid + 1];
        float degsum = 0.f;
        int p = beg + g;
        for (; p + 16 < end; p += 32) {  // 2 edges in flight per group
            int s1 = __builtin_nontemporal_load(&meta[p].x);
            int s2 = __builtin_nontemporal_load(&meta[p + 16].x);
            half8 a0 = *(const half8*)(uvh + (size_t)s1 * 128 + c * 16);
            half8 a1 = *(const half8*)(uvh + (size_t)s1 * 128 + c * 16 + 8);
            half8 b0 = *(const half8*)(uvh + (size_t)s2 * 128 + c * 16);
            half8 b1h = *(const half8*)(uvh + (size_t)s2 * 128 + c * 16 + 8);
            float p1 = 0.f, p2 = 0.f;
#pragma unroll
            for (int j = 0; j < 8; ++j) {
                float h1 = (float)a0[j] + vv[j];
                float h2 = (float)a1[j] + vv[8 + j];
                float h3 = (float)b0[j] + vv[j];
                float h4 = (float)b1h[j] + vv[8 + j];
                h1 = h1 > 0.f ? h1 : 0.f; h2 = h2 > 0.f ? h2 : 0.f;
                h3 = h3 > 0.f ? h3 : 0.f; h4 = h4 > 0.f ? h4 : 0.f;
                p1 += h1 * w2v[j] + h2 * w2v[8 + j];
                p2 += h3 * w2v[j] + h4 * w2v[8 + j];
            }
            p1 += __shfl_xor(p1, 1, 64); p2 += __shfl_xor(p2, 1, 64);
            p1 += __shfl_xor(p1, 2, 64); p2 += __shfl_xor(p2, 2, 64);
            if (c == 0) {
                float e1 = 1.f / (1.f + __expf(-(p1 + b2)));
                float e2 = 1.f / (1.f + __expf(-(p2 + b2)));
                meta[p].y = __float_as_int(e1);
                meta[p + 16].y = __float_as_int(e2);
                degsum += e1 + e2;
            }
        }
        if (p < end) {
            int s1 = __builtin_nontemporal_load(&meta[p].x);
            half8 a0 = *(const half8*)(uvh + (size_t)s1 * 128 + c * 16);
            half8 a1 = *(const half8*)(uvh + (size_t)s1 * 128 + c * 16 + 8);
            float p1 = 0.f;
#pragma unroll
            for (int j = 0; j < 8; ++j) {
                float h1 = (float)a0[j] + vv[j];
                float h2 = (float)a1[j] + vv[8 + j];
                h1 = h1 > 0.f ? h1 : 0.f; h2 = h2 > 0.f ? h2 : 0.f;
                p1 += h1 * w2v[j] + h2 * w2v[8 + j];
            }
            p1 += __shfl_xor(p1, 1, 64);
            p1 += __shfl_xor(p1, 2, 64);
            if (c == 0) {
                float e1 = 1.f / (1.f + __expf(-(p1 + b2)));
                meta[p].y = __float_as_int(e1);
                degsum += e1;
            }
        }
        degsum += __shfl_xor(degsum, 4, 64);
        degsum += __shfl_xor(degsum, 8, 64);
        degsum += __shfl_xor(degsum, 16, 64);
        degsum += __shfl_xor(degsum, 32, 64);
        if (lane == 0) deg[wid] = 1.f + degsum;
    }
}

// ---------------- GCN feature transform: xl' = dinv * (A_in @ W^T) (fp16) ----------------
__global__ __launch_bounds__(256) void k_gemm(
    const __hip_bfloat16* __restrict__ A, const __hip_bfloat16* __restrict__ Wb,
    const float* __restrict__ deg, _Float16* __restrict__ xlh) {
    const int lane = threadIdx.x & 63;
    const int wave = threadIdx.x >> 6;
    const int col = lane & 15;
    const int quad = lane >> 4;

    short8 bfrag[4][8];
    const short* wp = (const short*)Wb;
#pragma unroll
    for (int tt = 0; tt < 8; ++tt) {
        int row = tt * 16 + col;
#pragma unroll
        for (int kk = 0; kk < 4; ++kk)
            bfrag[kk][tt] = *(const short8*)(wp + row * 128 + kk * 32 + quad * 8);
    }
    int tile = blockIdx.x * 4 + wave;
    if (tile >= NN / 16) return;  // 3125 tiles
    int base = tile * 16;
    const short* xs = (const short*)A;

    floatx4 acc[8];
#pragma unroll
    for (int t = 0; t < 8; ++t) acc[t] = (floatx4){0.f, 0.f, 0.f, 0.f};
#pragma unroll
    for (int kk = 0; kk < 4; ++kk) {
        short8 afrag = *(const short8*)(xs + (size_t)(base + col) * 128 + kk * 32 + quad * 8);
#pragma unroll
        for (int tt = 0; tt < 8; ++tt)
            acc[tt] = __builtin_amdgcn_mfma_f32_16x16x32_bf16(afrag, bfrag[kk][tt], acc[tt], 0, 0, 0);
    }
    float di[4];
#pragma unroll
    for (int r = 0; r < 4; ++r) di[r] = rsqrtf(deg[base + quad * 4 + r]);
#pragma unroll
    for (int tt = 0; tt < 8; ++tt) {
        int n = tt * 16 + col;
#pragma unroll
        for (int r = 0; r < 4; ++r) {
            int row = base + quad * 4 + r;
            xlh[(size_t)row * 128 + n] = (_Float16)(di[r] * acc[tt][r]);
        }
    }
}

// ---------------- scatter core: 8 edge-groups of 8 lanes, 16 features/lane ----------------
// xlh pre-scaled by dinv[src]; coef = ew (meta.y). acc[16] per lane.
__device__ __forceinline__ void scatter_core(
    const int* __restrict__ rowptr, const int2* __restrict__ meta,
    const _Float16* __restrict__ xlh, int wid, int g, int c, float acc[16]) {
    int beg = rowptr[wid], end = rowptr[wid + 1];
    int p = beg + g;
    for (; p + 8 < end; p += 16) {  // 2 edges in flight per group
        long long m1 = __builtin_nontemporal_load((const long long*)&meta[p]);
        long long m2 = __builtin_nontemporal_load((const long long*)&meta[p + 8]);
        int s1 = (int)m1, s2 = (int)m2;
        float c1 = __int_as_float((int)(m1 >> 32)), c2 = __int_as_float((int)(m2 >> 32));
        half8 a0 = *(const half8*)(xlh + (size_t)s1 * 128 + c * 16);
        half8 a1 = *(const half8*)(xlh + (size_t)s1 * 128 + c * 16 + 8);
        half8 b0 = *(const half8*)(xlh + (size_t)s2 * 128 + c * 16);
        half8 b1 = *(const half8*)(xlh + (size_t)s2 * 128 + c * 16 + 8);
#pragma unroll
        for (int j = 0; j < 8; ++j) {
            acc[j] += c1 * (float)a0[j] + c2 * (float)b0[j];
            acc[8 + j] += c1 * (float)a1[j] + c2 * (float)b1[j];
        }
    }
    if (p < end) {
        long long m1 = __builtin_nontemporal_load((const long long*)&meta[p]);
        int s1 = (int)m1;
        float c1 = __int_as_float((int)(m1 >> 32));
        half8 a0 = *(const half8*)(xlh + (size_t)s1 * 128 + c * 16);
        half8 a1 = *(const half8*)(xlh + (size_t)s1 * 128 + c * 16 + 8);
#pragma unroll
        for (int j = 0; j < 8; ++j) {
            acc[j] += c1 * (float)a0[j];
            acc[8 + j] += c1 * (float)a1[j];
        }
    }
#pragma unroll
    for (int j = 0; j < 16; ++j) {
        acc[j] += __shfl_xor(acc[j], 8, 64);
        acc[j] += __shfl_xor(acc[j], 16, 64);
        acc[j] += __shfl_xor(acc[j], 32, 64);
    }
}

// mid-layer scatter: epilogue reconstructs bias + self-loop, emits relu as bf16
__global__ __launch_bounds__(256) void k_scatter_mid(
    const int* __restrict__ rowptr, const int2* __restrict__ meta,
    const float* __restrict__ deg, const _Float16* __restrict__ xlh,
    const float* __restrict__ bias, __hip_bfloat16* __restrict__ xb2,
    int* __restrict__ ctr) {
    const int lane = threadIdx.x & 63;
    const int g = lane >> 3, c = lane & 7;
    for (;;) {
        int wid;
        if (lane == 0) wid = atomicAdd(ctr, 1);
        wid = __shfl(wid, 0, 64);
        if (wid >= NN) break;
        float acc[16];
#pragma unroll
        for (int j = 0; j < 16; ++j) acc[j] = 0.f;
        scatter_core(rowptr, meta, xlh, wid, g, c, acc);
        if (g == 0) {
            float dn = rsqrtf(deg[wid]);
            half8 sv0 = *(const half8*)(xlh + (size_t)wid * 128 + c * 16);
            half8 sv1 = *(const half8*)(xlh + (size_t)wid * 128 + c * 16 + 8);
            const float4* bp = (const float4*)(bias + c * 16);
            short8 o0, o1;
#pragma unroll
            for (int q = 0; q < 2; ++q) {
                float4 ba = bp[q * 2], bb = bp[q * 2 + 1];
                float bv[8] = {ba.x, ba.y, ba.z, ba.w, bb.x, bb.y, bb.z, bb.w};
#pragma unroll
                for (int j = 0; j < 8; ++j) {
                    float sj = (q == 0) ? (float)sv0[j] : (float)sv1[j];
                    float t = bv[j] + dn * (sj + acc[q * 8 + j]);
                    t = t > 0.f ? t : 0.f;
                    if (q == 0) o0[j] = bf16_bits(t); else o1[j] = bf16_bits(t);
                }
            }
            *(short8*)((short*)xb2 + (size_t)wid * 128 + c * 16) = o0;
            *(short8*)((short*)xb2 + (size_t)wid * 128 + c * 16 + 8) = o1;
        }
    }
}

// final scatter fused with output head: sigmoid(relu(h2) @ Wlin^T + blin)
__global__ __launch_bounds__(256) void k_scatter_out(
    const int* __restrict__ rowptr, const int2* __restrict__ meta,
    const float* __restrict__ deg, const _Float16* __restrict__ xlh,
    const float* __restrict__ bias, const float* __restrict__ wlin,
    const float* __restrict__ blin, float* __restrict__ out, int* __restrict__ ctr) {
    const int lane = threadIdx.x & 63;
    const int g = lane >> 3, c = lane & 7;
    for (;;) {
        int wid;
        if (lane == 0) wid = atomicAdd(ctr, 1);
        wid = __shfl(wid, 0, 64);
        if (wid >= NN) break;
        float acc[16];
#pragma unroll
        for (int j = 0; j < 16; ++j) acc[j] = 0.f;
        scatter_core(rowptr, meta, xlh, wid, g, c, acc);
        if (g == 0) {
            float dn = rsqrtf(deg[wid]);
            half8 sv0 = *(const half8*)(xlh + (size_t)wid * 128 + c * 16);
            half8 sv1 = *(const half8*)(xlh + (size_t)wid * 128 + c * 16 + 8);
            const float4* bp = (const float4*)(bias + c * 16);
            float p0 = 0.f, p1 = 0.f;
#pragma unroll
            for (int q = 0; q < 2; ++q) {
                float4 ba = bp[q * 2], bb = bp[q * 2 + 1];
                float bv[8] = {ba.x, ba.y, ba.z, ba.w, bb.x, bb.y, bb.z, bb.w};
#pragma unroll
                for (int j = 0; j < 8; ++j) {
                    float sj = (q == 0) ? (float)sv0[j] : (float)sv1[j];
                    float t = bv[j] + dn * (sj + acc[q * 8 + j]);
                    t = t > 0.f ? t : 0.f;
                    int n = c * 16 + q * 8 + j;
                    p0 += t * wlin[n];
                    p1 += t * wlin[128 + n];
                }
            }
            p0 += __shfl_xor(p0, 1, 64); p1 += __shfl_xor(p1, 1, 64);
            p0 += __shfl_xor(p0, 2, 64); p1 += __shfl_xor(p1, 2, 64);
            p0 += __shfl_xor(p0, 4, 64); p1 += __shfl_xor(p1, 4, 64);
            if (c == 0) {
                out[wid * 2 + 0] = 1.f / (1.f + __expf(-(p0 + blin[0])));
                out[wid * 2 + 1] = 1.f / (1.f + __expf(-(p1 + blin[1])));
            }
        }
    }
}

// ---------------- host launcher ----------------

extern "C" void kernel_launch(void* const* d_in, const int* in_sizes, int n_in,
                              void* d_out, int out_size, void* d_ws, size_t ws_size,
                              hipStream_t stream) {
    const float* x = (const float*)d_in[0];
    const int* eidx_raw = (const int*)d_in[1];
    const float* W_p1 = (const float*)d_in[2];
    const float* b_p1 = (const float*)d_in[3];
    const float* W_p2 = (const float*)d_in[4];
    const float* b_p2 = (const float*)d_in[5];
    const float* W1 = (const float*)d_in[6];
    const float* b1 = (const float*)d_in[7];
    const float* W2 = (const float*)d_in[8];
    const float* b2 = (const float*)d_in[9];
    const float* W_lin = (const float*)d_in[10];
    const float* b_lin = (const float*)d_in[11];
    float* out = (float*)d_out;

    char* ws = (char*)d_ws;
    size_t off = 0;
    auto alloc = [&](size_t bytes) -> void* {
        off = (off + 255) & ~(size_t)255;
        void* p = ws + off;
        off += bytes;
        return p;
    };
    float* deg = (float*)alloc(NN * 4);
    int* rowptr = (int*)alloc((NN + 1) * 4);
    int* cursor = (int*)alloc(NN * 4);
    int* count = (int*)alloc(NN * 4);
    int* flag = (int*)alloc(4);
    int* pub = (int*)alloc(98 * 4);
    int* ctrs = (int*)alloc(3 * 4);
    int2* meta = (int2*)alloc((size_t)NE * 8);
    __hip_bfloat16* xb = (__hip_bfloat16*)alloc((size_t)NN * 128 * 2);  // reused as xb2
    _Float16* xlh = (_Float16*)alloc((size_t)NN * 128 * 2);
    _Float16* uvh = (_Float16*)alloc((size_t)NN * 128 * 2);
    __hip_bfloat16* wcatb = (__hip_bfloat16*)alloc(128 * 128 * 2);
    __hip_bfloat16* w1b = (__hip_bfloat16*)alloc(128 * 128 * 2);
    __hip_bfloat16* w2b = (__hip_bfloat16*)alloc(128 * 128 * 2);

    const int TB = 256;
    int gN = (NN + TB - 1) / TB;  // 196
    int gE = (NE + TB - 1) / TB;  // 2344

    k_init_cvt<<<gN, TB, 0, stream>>>(eidx_raw, count, flag, pub, ctrs, W_p1, W1, W2,
                                      wcatb, w1b, w2b);
    k_uv_count<<<GG + gE, TB, 0, stream>>>(x, wcatb, b_p1, uvh, xb, eidx_raw, flag, count);
    k_scan<<<98, 512, 0, stream>>>(count, rowptr, cursor, pub);
    k_fill<<<gE, TB, 0, stream>>>(eidx_raw, flag, cursor, meta);

    k_policy_csr<<<PGRID, TB, 0, stream>>>(uvh, W_p2, b_p2, rowptr, meta, deg, &ctrs[0]);

    // layer 1 (dinv folded into xlh)
    k_gemm<<<GG, TB, 0, stream>>>(xb, w1b, deg, xlh);
    k_scatter_mid<<<PGRID, TB, 0, stream>>>(rowptr, meta, deg, xlh, b1, xb, &ctrs[1]);
    // layer 2
    k_gemm<<<GG, TB, 0, stream>>>(xb, w2b, deg, xlh);
    k_scatter_out<<<PGRID, TB, 0, stream>>>(rowptr, meta, deg, xlh, b2, W_lin, b_lin, out,
                                            &ctrs[2]);
}

// Round 7
// 302.372 us; speedup vs baseline: 7.3450x; 7.3450x over previous
//
#include <hip/hip_runtime.h>
#include <hip/hip_bf16.h>

#define NN 50000
#define NE 600000
#define GG 782  // ceil((NN/16)/4) gemm blocks

typedef __attribute__((ext_vector_type(8))) short short8;     // 8 bf16 (4 VGPRs)
typedef __attribute__((ext_vector_type(8))) _Float16 half8;   // 8 fp16
typedef __attribute__((ext_vector_type(4))) float floatx4;    // 4 f32 acc

__device__ __forceinline__ short bf16_bits(float v) {
    __hip_bfloat16 h = __float2bfloat16(v);
    return *reinterpret_cast<short*>(&h);
}

// ---------------- init: zero count/pub + detect layout + convert weights ----------------
__global__ void k_init_cvt(const int* __restrict__ raw, int* __restrict__ count,
                           int* __restrict__ flag, int* __restrict__ pub,
                           const float* __restrict__ wp1,
                           const float* __restrict__ w1, const float* __restrict__ w2,
                           __hip_bfloat16* __restrict__ wcatb, __hip_bfloat16* __restrict__ w1b,
                           __hip_bfloat16* __restrict__ w2b) {
    int i = blockIdx.x * blockDim.x + threadIdx.x;
    if (i < NN) count[i] = 0;
    if (i < 98) pub[i] = 0;
    if (i < 16384) {
        int r = i >> 7, c = i & 127;
        float v = (r < 64) ? wp1[r * 256 + c] : wp1[(r - 64) * 256 + 128 + c];
        wcatb[i] = __float2bfloat16(v);
    } else if (i < 32768) {
        w1b[i - 16384] = __float2bfloat16(w1[i - 16384]);
    } else if (i < 49152) {
        w2b[i - 32768] = __float2bfloat16(w2[i - 32768]);
    }
    if (blockIdx.x == 0) {
        if (threadIdx.x == 0) *flag = 0;
        __syncthreads();
        int any = 0;
        for (int j = threadIdx.x; j < 1024; j += 256) any |= raw[2 * j + 1];
        if (any) atomicOr(flag, 1);  // flag=1 -> int32 layout
    }
}

// ---------------- merged: gemm_uv (blocks < GG) + degree count (rest) ----------------
__global__ __launch_bounds__(256) void k_uv_count(
    const float* __restrict__ x, const __hip_bfloat16* __restrict__ Wb,
    const float* __restrict__ bp1, _Float16* __restrict__ uvh,
    __hip_bfloat16* __restrict__ xb, const int* __restrict__ raw,
    const int* __restrict__ flag, int* __restrict__ count) {
    if (blockIdx.x >= GG) {
        int e = (blockIdx.x - GG) * blockDim.x + threadIdx.x;
        if (e < NE) {
            int d = (*flag) ? raw[NE + e] : (int)((const long long*)raw)[NE + e];
            atomicAdd(&count[d], 1);
        }
        return;
    }
    const int lane = threadIdx.x & 63;
    const int wave = threadIdx.x >> 6;
    const int col = lane & 15;
    const int quad = lane >> 4;

    short8 bfrag[4][8];
    const short* wp = (const short*)Wb;
#pragma unroll
    for (int tt = 0; tt < 8; ++tt) {
        int row = tt * 16 + col;
#pragma unroll
        for (int kk = 0; kk < 4; ++kk)
            bfrag[kk][tt] = *(const short8*)(wp + row * 128 + kk * 32 + quad * 8);
    }
    int tile = blockIdx.x * 4 + wave;
    if (tile >= NN / 16) return;
    int base = tile * 16;

    floatx4 acc[8];
#pragma unroll
    for (int t = 0; t < 8; ++t) acc[t] = (floatx4){0.f, 0.f, 0.f, 0.f};
#pragma unroll
    for (int kk = 0; kk < 4; ++kk) {
        const float* xrow = x + (size_t)(base + col) * 128 + kk * 32 + quad * 8;
        float4 f0 = ((const float4*)xrow)[0];
        float4 f1 = ((const float4*)xrow)[1];
        short8 afrag;
        afrag[0] = bf16_bits(f0.x); afrag[1] = bf16_bits(f0.y);
        afrag[2] = bf16_bits(f0.z); afrag[3] = bf16_bits(f0.w);
        afrag[4] = bf16_bits(f1.x); afrag[5] = bf16_bits(f1.y);
        afrag[6] = bf16_bits(f1.z); afrag[7] = bf16_bits(f1.w);
        *(short8*)((short*)xb + (size_t)(base + col) * 128 + kk * 32 + quad * 8) = afrag;
#pragma unroll
        for (int tt = 0; tt < 8; ++tt)
            acc[tt] = __builtin_amdgcn_mfma_f32_16x16x32_bf16(afrag, bfrag[kk][tt], acc[tt], 0, 0, 0);
    }
#pragma unroll
    for (int tt = 0; tt < 8; ++tt) {
        int n = tt * 16 + col;
        float badd = (tt >= 4) ? bp1[n - 64] : 0.f;
#pragma unroll
        for (int r = 0; r < 4; ++r) {
            int row = base + quad * 4 + r;
            uvh[(size_t)row * 128 + n] = (_Float16)(acc[tt][r] + badd);
        }
    }
}

// ---------------- single-kernel scan (decoupled lookback) + finalize ----------------
// pub[b] = block_total + 1 (0 = not ready). 98 blocks co-resident -> spin is safe.
__global__ __launch_bounds__(512) void k_scan(const int* __restrict__ count,
                                              int* __restrict__ rowptr,
                                              int* __restrict__ cursor,
                                              int* __restrict__ pub) {
    __shared__ int s[512];
    __shared__ int pref[128];
    int tid = threadIdx.x, b = blockIdx.x;
    int i = b * 512 + tid;
    int c0 = (i < NN) ? count[i] : 0;
    s[tid] = c0;
    __syncthreads();
    for (int off = 1; off < 512; off <<= 1) {
        int t = (tid >= off) ? s[tid - off] : 0;
        __syncthreads();
        s[tid] += t;
        __syncthreads();
    }
    int incl_local = s[tid];
    if (tid == 511) atomicExch(&pub[b], s[511] + 1);  // publish block total
    if (tid < 128) pref[tid] = 0;
    if (tid < b) {
        int v;
        while ((v = atomicAdd(&pub[tid], 0)) == 0) __builtin_amdgcn_s_sleep(4);
        pref[tid] = v - 1;
    }
    __syncthreads();
    for (int off = 64; off > 0; off >>= 1) {
        if (tid < off) pref[tid] += pref[tid + off];
        __syncthreads();
    }
    int bp = pref[0];
    if (i < NN) {
        int incl = incl_local + bp;
        rowptr[i + 1] = incl;
        cursor[i] = incl - c0;
        if (i == 0) rowptr[0] = 0;
    }
}

// CSR fill from raw edges: meta[pos] = {src, junk} (policy fills .y)
__global__ void k_fill(const int* __restrict__ raw, const int* __restrict__ flag,
                       int* __restrict__ cursor, int2* __restrict__ meta) {
    int e = blockIdx.x * blockDim.x + threadIdx.x;
    if (e >= NE) return;
    int s, d;
    if (*flag) {
        s = raw[e];
        d = raw[NE + e];
    } else {
        const long long* r64 = (const long long*)raw;
        s = (int)r64[e];
        d = (int)r64[NE + e];
    }
    int pos = atomicAdd(&cursor[d], 1);
    meta[pos] = make_int2(s, 0);
}

// ---------------- policy MLP in CSR order: wave per dst node (static) ----------------
// v[dst] loaded once; per in-edge gather u[src]; ew -> meta.y; deg w/o atomics
__global__ __launch_bounds__(256) void k_policy_csr(
    const _Float16* __restrict__ uvh, const float* __restrict__ wp2,
    const float* __restrict__ bp2, const int* __restrict__ rowptr,
    int2* __restrict__ meta, float* __restrict__ deg) {
    int wid = (blockIdx.x * blockDim.x + threadIdx.x) >> 6;
    int lane = threadIdx.x & 63;
    if (wid >= NN) return;
    int g = lane >> 3, c = lane & 7;  // 8 edge-groups of 8 lanes
    half8 vh = *(const half8*)(uvh + (size_t)wid * 128 + 64 + c * 8);
    float vv[8], w2v[8];
    const float4* w2p = (const float4*)(wp2 + c * 8);
    float4 wa = w2p[0], wb = w2p[1];
    w2v[0] = wa.x; w2v[1] = wa.y; w2v[2] = wa.z; w2v[3] = wa.w;
    w2v[4] = wb.x; w2v[5] = wb.y; w2v[6] = wb.z; w2v[7] = wb.w;
#pragma unroll
    for (int j = 0; j < 8; ++j) vv[j] = (float)vh[j];
    float b2 = bp2[0];
    int beg = rowptr[wid], end = rowptr[wid + 1];
    float degsum = 0.f;
    int p = beg + g;
    for (; p + 8 < end; p += 16) {  // unroll 2: two edges in flight per group
        int s1 = meta[p].x, s2 = meta[p + 8].x;
        half8 u1 = *(const half8*)(uvh + (size_t)s1 * 128 + c * 8);
        half8 u2 = *(const half8*)(uvh + (size_t)s2 * 128 + c * 8);
        float p1 = 0.f, p2 = 0.f;
#pragma unroll
        for (int j = 0; j < 8; ++j) {
            float h1 = (float)u1[j] + vv[j];
            float h2 = (float)u2[j] + vv[j];
            h1 = h1 > 0.f ? h1 : 0.f;
            h2 = h2 > 0.f ? h2 : 0.f;
            p1 += h1 * w2v[j];
            p2 += h2 * w2v[j];
        }
        p1 += __shfl_xor(p1, 1, 64); p2 += __shfl_xor(p2, 1, 64);
        p1 += __shfl_xor(p1, 2, 64); p2 += __shfl_xor(p2, 2, 64);
        p1 += __shfl_xor(p1, 4, 64); p2 += __shfl_xor(p2, 4, 64);
        if (c == 0) {
            float e1 = 1.f / (1.f + __expf(-(p1 + b2)));
            float e2 = 1.f / (1.f + __expf(-(p2 + b2)));
            meta[p].y = __float_as_int(e1);
            meta[p + 8].y = __float_as_int(e2);
            degsum += e1 + e2;
        }
    }
    if (p < end) {
        int s1 = meta[p].x;
        half8 u1 = *(const half8*)(uvh + (size_t)s1 * 128 + c * 8);
        float p1 = 0.f;
#pragma unroll
        for (int j = 0; j < 8; ++j) {
            float h1 = (float)u1[j] + vv[j];
            h1 = h1 > 0.f ? h1 : 0.f;
            p1 += h1 * w2v[j];
        }
        p1 += __shfl_xor(p1, 1, 64);
        p1 += __shfl_xor(p1, 2, 64);
        p1 += __shfl_xor(p1, 4, 64);
        if (c == 0) {
            float e1 = 1.f / (1.f + __expf(-(p1 + b2)));
            meta[p].y = __float_as_int(e1);
            degsum += e1;
        }
    }
    degsum += __shfl_xor(degsum, 8, 64);
    degsum += __shfl_xor(degsum, 16, 64);
    degsum += __shfl_xor(degsum, 32, 64);
    if (lane == 0) deg[wid] = 1.f + degsum;
}

// ---------------- GCN feature transform: xl' = dinv * (A_in @ W^T) (fp16) ----------------
__global__ __launch_bounds__(256) void k_gemm(
    const __hip_bfloat16* __restrict__ A, const __hip_bfloat16* __restrict__ Wb,
    const float* __restrict__ deg, _Float16* __restrict__ xlh) {
    const int lane = threadIdx.x & 63;
    const int wave = threadIdx.x >> 6;
    const int col = lane & 15;
    const int quad = lane >> 4;

    short8 bfrag[4][8];
    const short* wp = (const short*)Wb;
#pragma unroll
    for (int tt = 0; tt < 8; ++tt) {
        int row = tt * 16 + col;
#pragma unroll
        for (int kk = 0; kk < 4; ++kk)
            bfrag[kk][tt] = *(const short8*)(wp + row * 128 + kk * 32 + quad * 8);
    }
    int tile = blockIdx.x * 4 + wave;
    if (tile >= NN / 16) return;  // 3125 tiles
    int base = tile * 16;
    const short* xs = (const short*)A;

    floatx4 acc[8];
#pragma unroll
    for (int t = 0; t < 8; ++t) acc[t] = (floatx4){0.f, 0.f, 0.f, 0.f};
#pragma unroll
    for (int kk = 0; kk < 4; ++kk) {
        short8 afrag = *(const short8*)(xs + (size_t)(base + col) * 128 + kk * 32 + quad * 8);
#pragma unroll
        for (int tt = 0; tt < 8; ++tt)
            acc[tt] = __builtin_amdgcn_mfma_f32_16x16x32_bf16(afrag, bfrag[kk][tt], acc[tt], 0, 0, 0);
    }
    float di[4];
#pragma unroll
    for (int r = 0; r < 4; ++r) di[r] = rsqrtf(deg[base + quad * 4 + r]);
#pragma unroll
    for (int tt = 0; tt < 8; ++tt) {
        int n = tt * 16 + col;
#pragma unroll
        for (int r = 0; r < 4; ++r) {
            int row = base + quad * 4 + r;
            xlh[(size_t)row * 128 + n] = (_Float16)(di[r] * acc[tt][r]);
        }
    }
}

// ---------------- scatter core: wave per node, 4 edge-groups of 16 lanes ----------------
// xlh pre-scaled by dinv[src]; coef = ew (meta.y)
__device__ __forceinline__ void scatter_core(
    const int* __restrict__ rowptr, const int2* __restrict__ meta,
    const _Float16* __restrict__ xlh, int wid, int g, int c, float acc[8]) {
    int beg = rowptr[wid], end = rowptr[wid + 1];
    int p = beg + g;
    for (; p + 12 < end; p += 16) {
        int2 m1 = meta[p], m2 = meta[p + 4], m3 = meta[p + 8], m4 = meta[p + 12];
        half8 r1 = *(const half8*)(xlh + (size_t)m1.x * 128 + c * 8);
        half8 r2 = *(const half8*)(xlh + (size_t)m2.x * 128 + c * 8);
        half8 r3 = *(const half8*)(xlh + (size_t)m3.x * 128 + c * 8);
        half8 r4 = *(const half8*)(xlh + (size_t)m4.x * 128 + c * 8);
        float c1 = __int_as_float(m1.y), c2 = __int_as_float(m2.y);
        float c3 = __int_as_float(m3.y), c4 = __int_as_float(m4.y);
#pragma unroll
        for (int j = 0; j < 8; ++j)
            acc[j] += c1 * (float)r1[j] + c2 * (float)r2[j] + c3 * (float)r3[j] + c4 * (float)r4[j];
    }
    for (; p + 4 < end; p += 8) {
        int2 m1 = meta[p], m2 = meta[p + 4];
        half8 r1 = *(const half8*)(xlh + (size_t)m1.x * 128 + c * 8);
        half8 r2 = *(const half8*)(xlh + (size_t)m2.x * 128 + c * 8);
        float c1 = __int_as_float(m1.y), c2 = __int_as_float(m2.y);
#pragma unroll
        for (int j = 0; j < 8; ++j) acc[j] += c1 * (float)r1[j] + c2 * (float)r2[j];
    }
    if (p < end) {
        int2 m1 = meta[p];
        half8 r1 = *(const half8*)(xlh + (size_t)m1.x * 128 + c * 8);
        float c1 = __int_as_float(m1.y);
#pragma unroll
        for (int j = 0; j < 8; ++j) acc[j] += c1 * (float)r1[j];
    }
#pragma unroll
    for (int j = 0; j < 8; ++j) {
        acc[j] += __shfl_xor(acc[j], 16, 64);
        acc[j] += __shfl_xor(acc[j], 32, 64);
    }
}

// mid-layer scatter: epilogue reconstructs bias + self-loop, emits relu as bf16
__global__ __launch_bounds__(256) void k_scatter_mid(
    const int* __restrict__ rowptr, const int2* __restrict__ meta,
    const float* __restrict__ deg, const _Float16* __restrict__ xlh,
    const float* __restrict__ bias, __hip_bfloat16* __restrict__ xb2) {
    int wid = (blockIdx.x * blockDim.x + threadIdx.x) >> 6;
    int lane = threadIdx.x & 63;
    if (wid >= NN) return;
    int g = lane >> 4, c = lane & 15;
    float acc[8] = {0.f, 0.f, 0.f, 0.f, 0.f, 0.f, 0.f, 0.f};
    scatter_core(rowptr, meta, xlh, wid, g, c, acc);
    if (g == 0) {
        float dn = rsqrtf(deg[wid]);
        half8 sv = *(const half8*)(xlh + (size_t)wid * 128 + c * 8);  // pre-scaled self row
        const float4* bp = (const float4*)(bias + c * 8);
        float4 ba = bp[0], bb = bp[1];
        float bv[8] = {ba.x, ba.y, ba.z, ba.w, bb.x, bb.y, bb.z, bb.w};
        short8 o;
#pragma unroll
        for (int j = 0; j < 8; ++j) {
            float t = bv[j] + dn * ((float)sv[j] + acc[j]);
            t = t > 0.f ? t : 0.f;
            o[j] = bf16_bits(t);
        }
        *(short8*)((short*)xb2 + (size_t)wid * 128 + c * 8) = o;
    }
}

// final scatter fused with output head: sigmoid(relu(h2) @ Wlin^T + blin)
__global__ __launch_bounds__(256) void k_scatter_out(
    const int* __restrict__ rowptr, const int2* __restrict__ meta,
    const float* __restrict__ deg, const _Float16* __restrict__ xlh,
    const float* __restrict__ bias, const float* __restrict__ wlin,
    const float* __restrict__ blin, float* __restrict__ out) {
    int wid = (blockIdx.x * blockDim.x + threadIdx.x) >> 6;
    int lane = threadIdx.x & 63;
    if (wid >= NN) return;
    int g = lane >> 4, c = lane & 15;
    float acc[8] = {0.f, 0.f, 0.f, 0.f, 0.f, 0.f, 0.f, 0.f};
    scatter_core(rowptr, meta, xlh, wid, g, c, acc);
    if (g == 0) {
        float dn = rsqrtf(deg[wid]);
        half8 sv = *(const half8*)(xlh + (size_t)wid * 128 + c * 8);
        const float4* bp = (const float4*)(bias + c * 8);
        float4 ba = bp[0], bb = bp[1];
        float bv[8] = {ba.x, ba.y, ba.z, ba.w, bb.x, bb.y, bb.z, bb.w};
        float p0 = 0.f, p1 = 0.f;
#pragma unroll
        for (int j = 0; j < 8; ++j) {
            float t = bv[j] + dn * ((float)sv[j] + acc[j]);
            t = t > 0.f ? t : 0.f;
            p0 += t * wlin[c * 8 + j];
            p1 += t * wlin[128 + c * 8 + j];
        }
#pragma unroll
        for (int off = 1; off < 16; off <<= 1) {
            p0 += __shfl_xor(p0, off, 64);
            p1 += __shfl_xor(p1, off, 64);
        }
        if (c == 0) {
            out[wid * 2 + 0] = 1.f / (1.f + __expf(-(p0 + blin[0])));
            out[wid * 2 + 1] = 1.f / (1.f + __expf(-(p1 + blin[1])));
        }
    }
}

// ---------------- host launcher ----------------

extern "C" void kernel_launch(void* const* d_in, const int* in_sizes, int n_in,
                              void* d_out, int out_size, void* d_ws, size_t ws_size,
                              hipStream_t stream) {
    const float* x = (const float*)d_in[0];
    const int* eidx_raw = (const int*)d_in[1];
    const float* W_p1 = (const float*)d_in[2];
    const float* b_p1 = (const float*)d_in[3];
    const float* W_p2 = (const float*)d_in[4];
    const float* b_p2 = (const float*)d_in[5];
    const float* W1 = (const float*)d_in[6];
    const float* b1 = (const float*)d_in[7];
    const float* W2 = (const float*)d_in[8];
    const float* b2 = (const float*)d_in[9];
    const float* W_lin = (const float*)d_in[10];
    const float* b_lin = (const float*)d_in[11];
    float* out = (float*)d_out;

    char* ws = (char*)d_ws;
    size_t off = 0;
    auto alloc = [&](size_t bytes) -> void* {
        off = (off + 255) & ~(size_t)255;
        void* p = ws + off;
        off += bytes;
        return p;
    };
    float* deg = (float*)alloc(NN * 4);
    int* rowptr = (int*)alloc((NN + 1) * 4);
    int* cursor = (int*)alloc(NN * 4);
    int* count = (int*)alloc(NN * 4);
    int* flag = (int*)alloc(4);
    int* pub = (int*)alloc(98 * 4);
    int2* meta = (int2*)alloc((size_t)NE * 8);
    __hip_bfloat16* xb = (__hip_bfloat16*)alloc((size_t)NN * 128 * 2);  // reused as xb2
    _Float16* xlh = (_Float16*)alloc((size_t)NN * 128 * 2);
    _Float16* uvh = (_Float16*)alloc((size_t)NN * 128 * 2);
    __hip_bfloat16* wcatb = (__hip_bfloat16*)alloc(128 * 128 * 2);
    __hip_bfloat16* w1b = (__hip_bfloat16*)alloc(128 * 128 * 2);
    __hip_bfloat16* w2b = (__hip_bfloat16*)alloc(128 * 128 * 2);

    const int TB = 256;
    int gN = (NN + TB - 1) / TB;  // 196
    int gE = (NE + TB - 1) / TB;  // 2344
    int gS = (NN + 3) / 4;        // 12500

    k_init_cvt<<<gN, TB, 0, stream>>>(eidx_raw, count, flag, pub, W_p1, W1, W2,
                                      wcatb, w1b, w2b);
    k_uv_count<<<GG + gE, TB, 0, stream>>>(x, wcatb, b_p1, uvh, xb, eidx_raw, flag, count);
    k_scan<<<98, 512, 0, stream>>>(count, rowptr, cursor, pub);
    k_fill<<<gE, TB, 0, stream>>>(eidx_raw, flag, cursor, meta);

    k_policy_csr<<<gS, TB, 0, stream>>>(uvh, W_p2, b_p2, rowptr, meta, deg);

    // layer 1 (dinv folded into xlh)
    k_gemm<<<GG, TB, 0, stream>>>(xb, w1b, deg, xlh);
    k_scatter_mid<<<gS, TB, 0, stream>>>(rowptr, meta, deg, xlh, b1, xb);
    // layer 2
    k_gemm<<<GG, TB, 0, stream>>>(xb, w2b, deg, xlh);
    k_scatter_out<<<gS, TB, 0, stream>>>(rowptr, meta, deg, xlh, b2, W_lin, b_lin, out);
}